// Round 4
// baseline (2382.881 us; speedup 1.0000x reference)
//
#include <hip/hip_runtime.h>
#include <hip/hip_bf16.h>
#include <cstdint>
#include <cstddef>

// Problem constants (fixed by the harness problem instance).
#define MM 8192
#define KK 4096
#define NN 12288

typedef __bf16 bf16x8 __attribute__((ext_vector_type(8)));
typedef float  f32x4  __attribute__((ext_vector_type(4)));

// fp32 -> bf16 round-to-nearest-even (finite inputs).
__device__ __forceinline__ unsigned short f2bf(float f) {
    union { float f; unsigned int u; } v; v.f = f;
    unsigned int r = v.u + 0x7fffu + ((v.u >> 16) & 1u);
    return (unsigned short)(r >> 16);
}

// async global->LDS, 16 B per lane. LDS dest is wave-uniform base + lane*16.
__device__ __forceinline__ void gload_lds16(const void* g, void* l) {
    __builtin_amdgcn_global_load_lds(
        (__attribute__((address_space(1))) void*)g,
        (__attribute__((address_space(3))) void*)l,
        16, 0, 0);
}

#define FENCE() asm volatile("" ::: "memory")
#define BARF()  do { FENCE(); __builtin_amdgcn_s_barrier(); FENCE(); } while (0)

// ---------------- pre-pass 1: input fp32 -> bf16 ----------------
__global__ __launch_bounds__(256) void cvt_a_kernel(
    const float* __restrict__ in, unsigned short* __restrict__ out)
{
    size_t i = (size_t)blockIdx.x * 256 + threadIdx.x;   // 8 elems / thread
    const float4* p = (const float4*)in;
    float4 x = p[2 * i], y = p[2 * i + 1];
    union { unsigned short h[8]; uint4 v; } u;
    u.h[0] = f2bf(x.x); u.h[1] = f2bf(x.y); u.h[2] = f2bf(x.z); u.h[3] = f2bf(x.w);
    u.h[4] = f2bf(y.x); u.h[5] = f2bf(y.y); u.h[6] = f2bf(y.z); u.h[7] = f2bf(y.w);
    ((uint4*)out)[i] = u.v;
}

// ---------------- pre-pass 2: dequant int4 codes -> bf16 [N,K] ----------------
__global__ __launch_bounds__(256) void dq_w_kernel(
    const int* __restrict__ w, const float* __restrict__ snz,
    unsigned short* __restrict__ out)
{
    size_t t = (size_t)blockIdx.x * 256 + threadIdx.x;   // 8 codes / thread
    int kc = (int)(t & (KK / 8 - 1));                    // K/8 = 512
    int n  = (int)(t >> 9);
    int g  = kc >> 2;                                    // 32 codes per group
    float2 sz = ((const float2*)snz)[(size_t)g * NN + n];  // {scale, zero}
    const int4* wp = (const int4*)w;
    int4 q0 = wp[2 * t], q1 = wp[2 * t + 1];
    union { unsigned short h[8]; uint4 v; } u;
    u.h[0] = f2bf((float)(q0.x - 8) * sz.x + sz.y);
    u.h[1] = f2bf((float)(q0.y - 8) * sz.x + sz.y);
    u.h[2] = f2bf((float)(q0.z - 8) * sz.x + sz.y);
    u.h[3] = f2bf((float)(q0.w - 8) * sz.x + sz.y);
    u.h[4] = f2bf((float)(q1.x - 8) * sz.x + sz.y);
    u.h[5] = f2bf((float)(q1.y - 8) * sz.x + sz.y);
    u.h[6] = f2bf((float)(q1.z - 8) * sz.x + sz.y);
    u.h[7] = f2bf((float)(q1.w - 8) * sz.x + sz.y);
    ((uint4*)out)[t] = u.v;
}

// ================= 256x256 GEMM, LDS/MFMA-overlapped schedule =================
// C[M,N] = A[M,K](bf16) * W[N,K](bf16)^T + bias, fp32 out.
// 8 waves (2M x 4N), wave output 128x64, acc[8][4] f32x4.
// LDS 160 KiB: Abuf x2 @ {0,32768}; Bbuf x3 @ 65536+{0,1,2}*32768.
// 128-B rows, chunk-XOR swizzle (phys = logical ^ (row&7)) on write-src & read.
//
// Register-pipelined A: aC = kk0 frags of tile t (read last tile),
// a1 = kk1 frags of t (read in super-phase A), aN = kk0 of t+1 (read in B).
// 4 clusters/tile, 6 ds_read_b128 each; b-reads FIRST so the MFMA's
// compiler-inserted lgkmcnt waits only on b (in-order DS completion) and the
// a-prefetch reads overlap the MFMA. EXCEPT cluster 2: a1[4..7] BEFORE b, so
// waiting on b proves ALL Abuf[t&1] reads drained before the barrier that
// precedes the in-place A(t+2) restage (rigorous drain, not timing luck).
// Barriers: 2/tile (end of each super-phase). vmcnt(4) mid-tile drains
// A(t+1) for the aN reads (the 4 newest outstanding = B(t+2) stages);
// vmcnt(0) once staging stops (t+2>=TT).
#define BM 256
#define BN 256
#define BK 64
#define TT (KK / BK)   // 64

__global__ __launch_bounds__(512, 2) void gemm256_kernel(
    const unsigned short* __restrict__ A,    // bf16 [M,K]
    const unsigned short* __restrict__ Bw,   // bf16 [N,K]
    const float* __restrict__ bias,          // [N]
    float* __restrict__ C)                   // fp32 [M,N]
{
    __shared__ char lds[163840];

    const int tid  = threadIdx.x;
    const int lane = tid & 63;
    const int wave = tid >> 6;            // 0..7
    const int wm   = wave >> 2;           // 0..1
    const int wn   = wave & 3;            // 0..3

    // XCD-aware swizzle (nwg = 32*48 = 1536, divisible by 8).
    const int NTN = NN / BN;              // 48
    const int nwg = (MM / BM) * NTN;      // 1536
    const int cpx = nwg >> 3;             // 192
    int wg = ((int)blockIdx.x & 7) * cpx + ((int)blockIdx.x >> 3);
    const int tm = wg / NTN;
    const int tn = wg - tm * NTN;

    f32x4 acc[8][4] = {};

    // ---- staging lane constants ----
    const int lrow = lane >> 3;
    const int lc   = (lane & 7) ^ lrow;
    const unsigned short* aSrc = A  + (size_t)(tm * BM + wave * 8 + lrow) * KK + lc * 8;
    const unsigned short* bSrc = Bw + (size_t)(tn * BN + wave * 8 + lrow) * KK + lc * 8;
    const int wblk = wave * 1024;

#define STAGE(srcBase, rowsOff, kOff, ldsPtr) do {                                          \
        gload_lds16((srcBase) + (size_t)(rowsOff) * KK + (kOff), (ldsPtr) + wblk);          \
        gload_lds16((srcBase) + (size_t)((rowsOff) + 64) * KK + (kOff), (ldsPtr) + 8192 + wblk); \
    } while (0)

    // ---- compute lane constants ----
    const int r7  = lane & 7;
    const int l15 = lane & 15;
    const int c0  = (((lane >> 4)    ) ^ r7) * 16;   // kk0 phys chunk byte
    const int c1  = (((lane >> 4) + 4) ^ r7) * 16;   // kk1 phys chunk byte
    const int aoff = (wm * 128 + l15) * 128;         // A row byte offset (mf adds 2048)
    const int boff = (wn * 64  + l15) * 128;         // B row byte offset (nf adds 2048)

    // ---- prologue: A(0),B(0),A(1),B(1); drain first 8; read aA = A(0)kk0 ----
    STAGE(aSrc, 0,   0, lds + 0);
    STAGE(aSrc, 128, 0, lds + 16384);
    STAGE(bSrc, 0,   0, lds + 65536);
    STAGE(bSrc, 128, 0, lds + 65536 + 16384);
    STAGE(aSrc, 0,   BK, lds + 32768);
    STAGE(aSrc, 128, BK, lds + 32768 + 16384);
    STAGE(bSrc, 0,   BK, lds + 65536 + 32768);
    STAGE(bSrc, 128, BK, lds + 65536 + 32768 + 16384);
    asm volatile("s_waitcnt vmcnt(8)" ::: "memory");
    BARF();

    bf16x8 aA[8], aB[8], a1[8];
#pragma unroll
    for (int mf = 0; mf < 8; ++mf)
        aA[mf] = *(const bf16x8*)(lds + aoff + mf * 2048 + c0);

#define MFMA8(AARR, BREG, NF)                                                     \
    _Pragma("unroll")                                                             \
    for (int mf = 0; mf < 8; ++mf)                                                \
        acc[mf][NF] = __builtin_amdgcn_mfma_f32_16x16x32_bf16(                    \
            AARR[mf], BREG, acc[mf][NF], 0, 0, 0);

#define TILE(T, BRD, AC, AN) do {                                                 \
    const char* Ab = lds + (((T) & 1) << 15);                                     \
    const char* Bb = lds + 65536 + ((BRD) << 15);                                 \
    int bs_ = (BRD) + 2; if (bs_ >= 3) bs_ -= 3;                                  \
    char* Bst = lds + 65536 + (bs_ << 15);                                        \
    char* Ast = lds + (((T) & 1) << 15);                                          \
    const char* An = lds + (((((T) + 1)) & 1) << 15);                             \
    const bool pf2 = (T) + 2 < TT;                                                \
    const bool pf1 = (T) + 1 < TT;                                                \
    const int kpf = ((T) + 2) * BK;                                               \
    /* ---- c1: b(kk0,n0,n1); a1[0..3]; stage B(t+2)h0; MFMA kk0 n0,n1 ---- */    \
    bf16x8 b00 = *(const bf16x8*)(Bb + boff + 0 * 2048 + c0);                     \
    bf16x8 b01 = *(const bf16x8*)(Bb + boff + 1 * 2048 + c0);                     \
    a1[0] = *(const bf16x8*)(Ab + aoff + 0 * 2048 + c1);                          \
    a1[1] = *(const bf16x8*)(Ab + aoff + 1 * 2048 + c1);                          \
    a1[2] = *(const bf16x8*)(Ab + aoff + 2 * 2048 + c1);                          \
    a1[3] = *(const bf16x8*)(Ab + aoff + 3 * 2048 + c1);                          \
    if (pf2) STAGE(bSrc, 0, kpf, Bst);                                            \
    __builtin_amdgcn_s_setprio(1);                                                \
    MFMA8(AC, b00, 0); MFMA8(AC, b01, 1);                                         \
    __builtin_amdgcn_s_setprio(0);                                                \
    /* ---- c2: a1[4..7] BEFORE b (drain proof); stage B(t+2)h1; MFMA ---- */     \
    a1[4] = *(const bf16x8*)(Ab + aoff + 4 * 2048 + c1);                          \
    a1[5] = *(const bf16x8*)(Ab + aoff + 5 * 2048 + c1);                          \
    a1[6] = *(const bf16x8*)(Ab + aoff + 6 * 2048 + c1);                          \
    a1[7] = *(const bf16x8*)(Ab + aoff + 7 * 2048 + c1);                          \
    bf16x8 b02 = *(const bf16x8*)(Bb + boff + 2 * 2048 + c0);                     \
    bf16x8 b03 = *(const bf16x8*)(Bb + boff + 3 * 2048 + c0);                     \
    if (pf2) STAGE(bSrc, 128, kpf, Bst + 16384);                                  \
    __builtin_amdgcn_s_setprio(1);                                                \
    MFMA8(AC, b02, 2); MFMA8(AC, b03, 3);                                         \
    __builtin_amdgcn_s_setprio(0);                                                \
    if (pf2) { asm volatile("s_waitcnt vmcnt(4)" ::: "memory"); }                 \
    else     { asm volatile("s_waitcnt vmcnt(0)" ::: "memory"); }                 \
    BARF();                                                                       \
    /* ---- c3: b(kk1,n0,n1); aN[0..3]=A(t+1)kk0; stage A(t+2)h0; MFMA ---- */    \
    bf16x8 b10 = *(const bf16x8*)(Bb + boff + 0 * 2048 + c1);                     \
    bf16x8 b11 = *(const bf16x8*)(Bb + boff + 1 * 2048 + c1);                     \
    if (pf1) {                                                                    \
        AN[0] = *(const bf16x8*)(An + aoff + 0 * 2048 + c0);                      \
        AN[1] = *(const bf16x8*)(An + aoff + 1 * 2048 + c0);                      \
        AN[2] = *(const bf16x8*)(An + aoff + 2 * 2048 + c0);                      \
        AN[3] = *(const bf16x8*)(An + aoff + 3 * 2048 + c0);                      \
    }                                                                             \
    if (pf2) STAGE(aSrc, 0, kpf, Ast);                                            \
    __builtin_amdgcn_s_setprio(1);                                                \
    MFMA8(a1, b10, 0); MFMA8(a1, b11, 1);                                         \
    __builtin_amdgcn_s_setprio(0);                                                \
    /* ---- c4: b(kk1,n2,n3); aN[4..7]; stage A(t+2)h1; MFMA ---- */              \
    bf16x8 b12 = *(const bf16x8*)(Bb + boff + 2 * 2048 + c1);                     \
    bf16x8 b13 = *(const bf16x8*)(Bb + boff + 3 * 2048 + c1);                     \
    if (pf1) {                                                                    \
        AN[4] = *(const bf16x8*)(An + aoff + 4 * 2048 + c0);                      \
        AN[5] = *(const bf16x8*)(An + aoff + 5 * 2048 + c0);                      \
        AN[6] = *(const bf16x8*)(An + aoff + 6 * 2048 + c0);                      \
        AN[7] = *(const bf16x8*)(An + aoff + 7 * 2048 + c0);                      \
    }                                                                             \
    if (pf2) STAGE(aSrc, 128, kpf, Ast + 16384);                                  \
    __builtin_amdgcn_s_setprio(1);                                                \
    MFMA8(a1, b12, 2); MFMA8(a1, b13, 3);                                         \
    __builtin_amdgcn_s_setprio(0);                                                \
    BARF();                                                                       \
} while (0)

    int bR = 0;   // t2 % 3
#pragma unroll 1
    for (int t2 = 0; t2 < TT; t2 += 2) {
        int bR1 = bR + 1; if (bR1 >= 3) bR1 -= 3;
        TILE(t2,     bR,  aA, aB);
        TILE(t2 + 1, bR1, aB, aA);
        bR = bR1 + 1; if (bR >= 3) bR -= 3;
    }
#undef TILE
#undef MFMA8
#undef STAGE

    // ---- epilogue: C/D layout col=lane&15, row=(lane>>4)*4+j; fuse bias ----
    const int crow = tm * BM + wm * 128 + (lane >> 4) * 4;
    const int ccol = tn * BN + wn * 64 + l15;
    float bv[4];
#pragma unroll
    for (int nf = 0; nf < 4; ++nf) bv[nf] = bias[ccol + nf * 16];
#pragma unroll
    for (int mf = 0; mf < 8; ++mf)
#pragma unroll
        for (int nf = 0; nf < 4; ++nf)
#pragma unroll
            for (int j = 0; j < 4; ++j)
                C[(size_t)(crow + mf * 16 + j) * NN + ccol + nf * 16] =
                    acc[mf][nf][j] + bv[nf];
}

// ================= fallback: fused 128x128 (R1, known-correct) =================
__global__ __launch_bounds__(256) void gemm_fused_kernel(
    const float* __restrict__ Af,
    const int* __restrict__ Wq,
    const float* __restrict__ snz,
    const float* __restrict__ bias,
    float* __restrict__ C)
{
    __shared__ alignas(16) unsigned short As[128 * 64];
    __shared__ alignas(16) unsigned short Bs[128 * 64];

    const int tid  = threadIdx.x;
    const int lane = tid & 63;
    const int wave = tid >> 6;

    const int NTN = NN / 128;
    const int nwg = (MM / 128) * NTN;
    const int cpx = nwg >> 3;
    int wg = ((int)blockIdx.x & 7) * cpx + ((int)blockIdx.x >> 3);
    const int tm = wg / NTN;
    const int tn = wg - tm * NTN;

    const int wm = wave >> 1, wn = wave & 1;

    f32x4 acc[4][4] = {};

    const int r7  = lane & 7;
    const int pc0 = (((lane >> 4)    ) ^ r7) * 16;
    const int pc1 = (((lane >> 4) + 4) ^ r7) * 16;
    const int arow = wm * 64 + (lane & 15);
    const int brow = wn * 64 + (lane & 15);
    const char* AsR = (const char*)As;
    const char* BsR = (const char*)Bs;

    const int frow = tid >> 1;
    const int fh   = tid & 1;
    const int frx  = frow & 7;

    for (int k0 = 0; k0 < KK; k0 += 64) {
        {
            const float* ap = Af + (size_t)(tm * 128 + frow) * KK + k0 + fh * 32;
#pragma unroll
            for (int c = 0; c < 4; ++c) {
                float4 x = ((const float4*)ap)[2 * c];
                float4 y = ((const float4*)ap)[2 * c + 1];
                union { unsigned short h[8]; uint4 v; } u;
                u.h[0] = f2bf(x.x); u.h[1] = f2bf(x.y); u.h[2] = f2bf(x.z); u.h[3] = f2bf(x.w);
                u.h[4] = f2bf(y.x); u.h[5] = f2bf(y.y); u.h[6] = f2bf(y.z); u.h[7] = f2bf(y.w);
                int lc2 = fh * 4 + c;
                *(uint4*)&As[frow * 64 + ((lc2 ^ frx) * 8)] = u.v;
            }
        }
        {
            const int nrow = tn * 128 + frow;
            const int* wp = Wq + (size_t)nrow * KK + k0 + fh * 32;
            float2 sz = ((const float2*)snz)[(size_t)((k0 >> 5) + fh) * NN + nrow];
#pragma unroll
            for (int c = 0; c < 4; ++c) {
                int4 q0 = ((const int4*)wp)[2 * c];
                int4 q1 = ((const int4*)wp)[2 * c + 1];
                union { unsigned short h[8]; uint4 v; } u;
                u.h[0] = f2bf((float)(q0.x - 8) * sz.x + sz.y);
                u.h[1] = f2bf((float)(q0.y - 8) * sz.x + sz.y);
                u.h[2] = f2bf((float)(q0.z - 8) * sz.x + sz.y);
                u.h[3] = f2bf((float)(q0.w - 8) * sz.x + sz.y);
                u.h[4] = f2bf((float)(q1.x - 8) * sz.x + sz.y);
                u.h[5] = f2bf((float)(q1.y - 8) * sz.x + sz.y);
                u.h[6] = f2bf((float)(q1.z - 8) * sz.x + sz.y);
                u.h[7] = f2bf((float)(q1.w - 8) * sz.x + sz.y);
                int lc2 = fh * 4 + c;
                *(uint4*)&Bs[frow * 64 + ((lc2 ^ frx) * 8)] = u.v;
            }
        }
        __syncthreads();
        {
            bf16x8 af[4], bfr[4];
#pragma unroll
            for (int x = 0; x < 4; ++x) {
                af[x]  = *(const bf16x8*)(AsR + (arow + x * 16) * 128 + pc0);
                bfr[x] = *(const bf16x8*)(BsR + (brow + x * 16) * 128 + pc0);
            }
#pragma unroll
            for (int mi = 0; mi < 4; ++mi)
#pragma unroll
                for (int ni = 0; ni < 4; ++ni)
                    acc[mi][ni] = __builtin_amdgcn_mfma_f32_16x16x32_bf16(
                        af[mi], bfr[ni], acc[mi][ni], 0, 0, 0);
        }
        {
            bf16x8 af[4], bfr[4];
#pragma unroll
            for (int x = 0; x < 4; ++x) {
                af[x]  = *(const bf16x8*)(AsR + (arow + x * 16) * 128 + pc1);
                bfr[x] = *(const bf16x8*)(BsR + (brow + x * 16) * 128 + pc1);
            }
#pragma unroll
            for (int mi = 0; mi < 4; ++mi)
#pragma unroll
                for (int ni = 0; ni < 4; ++ni)
                    acc[mi][ni] = __builtin_amdgcn_mfma_f32_16x16x32_bf16(
                        af[mi], bfr[ni], acc[mi][ni], 0, 0, 0);
        }
        __syncthreads();
    }

    const int crow = tm * 128 + wm * 64 + (lane >> 4) * 4;
    const int ccol = tn * 128 + wn * 64 + (lane & 15);
    float bv[4];
#pragma unroll
    for (int ni = 0; ni < 4; ++ni) bv[ni] = bias[ccol + ni * 16];
#pragma unroll
    for (int mi = 0; mi < 4; ++mi)
#pragma unroll
        for (int ni = 0; ni < 4; ++ni)
#pragma unroll
            for (int j = 0; j < 4; ++j)
                C[(size_t)(crow + mi * 16 + j) * NN + ccol + ni * 16] =
                    acc[mi][ni][j] + bv[ni];
}

extern "C" void kernel_launch(void* const* d_in, const int* in_sizes, int n_in,
                              void* d_out, int out_size, void* d_ws, size_t ws_size,
                              hipStream_t stream)
{
    const float* inA  = (const float*)d_in[0];   // [M,K] fp32
    const int*   Wq   = (const int*)d_in[1];     // [N,K] int codes
    const float* snz  = (const float*)d_in[2];   // [K/32,N,2] fp32
    const float* bias = (const float*)d_in[3];   // [N] fp32
    float* out = (float*)d_out;

    const size_t needA = (size_t)MM * KK * 2;
    const size_t needW = (size_t)NN * KK * 2;

    if (ws_size >= needA + needW) {
        unsigned short* Abf = (unsigned short*)d_ws;
        unsigned short* Wbf = (unsigned short*)((char*)d_ws + needA);
        cvt_a_kernel<<<(MM * KK / 8) / 256, 256, 0, stream>>>(inA, Abf);
        dq_w_kernel<<<(NN * KK / 8) / 256, 256, 0, stream>>>(Wq, snz, Wbf);
        gemm256_kernel<<<(MM / BM) * (NN / BN), 512, 0, stream>>>(Abf, Wbf, bias, out);
    } else {
        gemm_fused_kernel<<<(MM / 128) * (NN / 128), 256, 0, stream>>>(
            inA, Wq, snz, bias, out);
    }
}

// Round 5
// 813.547 us; speedup vs baseline: 2.9290x; 2.9290x over previous
//
#include <hip/hip_runtime.h>
#include <hip/hip_bf16.h>
#include <cstdint>
#include <cstddef>

// Problem constants (fixed by the harness problem instance).
#define MM 8192
#define KK 4096
#define NN 12288

typedef __bf16 bf16x8 __attribute__((ext_vector_type(8)));
typedef float  f32x4  __attribute__((ext_vector_type(4)));

// fp32 -> bf16 round-to-nearest-even (finite inputs).
__device__ __forceinline__ unsigned short f2bf(float f) {
    union { float f; unsigned int u; } v; v.f = f;
    unsigned int r = v.u + 0x7fffu + ((v.u >> 16) & 1u);
    return (unsigned short)(r >> 16);
}

// async global->LDS, 16 B per lane. LDS dest is wave-uniform base + lane*16.
__device__ __forceinline__ void gload_lds16(const void* g, void* l) {
    __builtin_amdgcn_global_load_lds(
        (__attribute__((address_space(1))) void*)g,
        (__attribute__((address_space(3))) void*)l,
        16, 0, 0);
}

#define FENCE() asm volatile("" ::: "memory")
#define LGKM0() asm volatile("s_waitcnt lgkmcnt(0)" ::: "memory")
#define BARF()  do { FENCE(); __builtin_amdgcn_s_barrier(); FENCE(); } while (0)

// ---------------- pre-pass 1: input fp32 -> bf16 ----------------
__global__ __launch_bounds__(256) void cvt_a_kernel(
    const float* __restrict__ in, unsigned short* __restrict__ out)
{
    size_t i = (size_t)blockIdx.x * 256 + threadIdx.x;   // 8 elems / thread
    const float4* p = (const float4*)in;
    float4 x = p[2 * i], y = p[2 * i + 1];
    union { unsigned short h[8]; uint4 v; } u;
    u.h[0] = f2bf(x.x); u.h[1] = f2bf(x.y); u.h[2] = f2bf(x.z); u.h[3] = f2bf(x.w);
    u.h[4] = f2bf(y.x); u.h[5] = f2bf(y.y); u.h[6] = f2bf(y.z); u.h[7] = f2bf(y.w);
    ((uint4*)out)[i] = u.v;
}

// ---------------- pre-pass 2: dequant int4 codes -> bf16 [N,K] ----------------
__global__ __launch_bounds__(256) void dq_w_kernel(
    const int* __restrict__ w, const float* __restrict__ snz,
    unsigned short* __restrict__ out)
{
    size_t t = (size_t)blockIdx.x * 256 + threadIdx.x;   // 8 codes / thread
    int kc = (int)(t & (KK / 8 - 1));                    // K/8 = 512
    int n  = (int)(t >> 9);
    int g  = kc >> 2;                                    // 32 codes per group
    float2 sz = ((const float2*)snz)[(size_t)g * NN + n];  // {scale, zero}
    const int4* wp = (const int4*)w;
    int4 q0 = wp[2 * t], q1 = wp[2 * t + 1];
    union { unsigned short h[8]; uint4 v; } u;
    u.h[0] = f2bf((float)(q0.x - 8) * sz.x + sz.y);
    u.h[1] = f2bf((float)(q0.y - 8) * sz.x + sz.y);
    u.h[2] = f2bf((float)(q0.z - 8) * sz.x + sz.y);
    u.h[3] = f2bf((float)(q0.w - 8) * sz.x + sz.y);
    u.h[4] = f2bf((float)(q1.x - 8) * sz.x + sz.y);
    u.h[5] = f2bf((float)(q1.y - 8) * sz.x + sz.y);
    u.h[6] = f2bf((float)(q1.z - 8) * sz.x + sz.y);
    u.h[7] = f2bf((float)(q1.w - 8) * sz.x + sz.y);
    ((uint4*)out)[t] = u.v;
}

// ================= 256x256 GEMM, 2-gate relaxed schedule =================
// C[M,N] = A[M,K](bf16) * W[N,K](bf16)^T + bias, fp32 out.
// 8 waves (2M x 4N), wave output 128x64, acc[8][4] f32x4 (AGPR).
// LDS 128 KiB: buffer b at b*65536 = {A: 32 KiB, B: 32 KiB}.
// 128-B rows, chunk-XOR swizzle (phys = logical ^ (row&7)) on write-src & read.
//
// Per K-tile, 4 clusters of 16 MFMA each, but only TWO barriers:
//  c1: ds b00,b01 + a0[8]; stage B(t+1) (both halves) -> other buf; MFMA a0 x b00,b01
//  c2: ds b02,b03;                                                  MFMA a0 x b02,b03
//  c3: ds a1[8] + b10,b11; LGKM0; BARRIER   <- A-drain gate: every wave executed
//      lgkmcnt(0) after issuing ALL its A(t)-reads (a0 in c1, a1 in c3), so all
//      A-buffer reads are complete block-wide before any A(t+2) stage issues.
//                                                                  MFMA a1 x b10,b11
//  c4: ds b12,b13; stage A(t+2) in-place (safe: after gate);        MFMA a1 x b12,b13
//      vmcnt(4); BARRIER                    <- tile gate: drains A(t+1) (staged
//      t-1 c4) and B(t+1) (staged t c1); only A(t+2)'s 4 loads stay in flight.
// No per-cluster barriers => compiler fine-schedules ds_read || MFMA and the
// 2 waves/SIMD slip against each other (read/MFMA overlap across waves).
// Live operand regs <= ~112 (a0 dies after c2) - no spill (R4 post-mortem).
#define BM 256
#define BN 256
#define BK 64
#define TT (KK / BK)   // 64

__global__ __launch_bounds__(512, 2) void gemm256_kernel(
    const unsigned short* __restrict__ A,    // bf16 [M,K]
    const unsigned short* __restrict__ Bw,   // bf16 [N,K]
    const float* __restrict__ bias,          // [N]
    float* __restrict__ C)                   // fp32 [M,N]
{
    __shared__ char lds[131072];

    const int tid  = threadIdx.x;
    const int lane = tid & 63;
    const int wave = tid >> 6;            // 0..7
    const int wm   = wave >> 2;           // 0..1
    const int wn   = wave & 3;            // 0..3

    // XCD-aware swizzle (nwg = 32*48 = 1536, divisible by 8).
    const int NTN = NN / BN;              // 48
    const int nwg = (MM / BM) * NTN;      // 1536
    const int cpx = nwg >> 3;             // 192
    int wg = ((int)blockIdx.x & 7) * cpx + ((int)blockIdx.x >> 3);
    const int tm = wg / NTN;
    const int tn = wg - tm * NTN;

    f32x4 acc[8][4] = {};

    // ---- staging lane constants (R2-proven geometry) ----
    const int lrow = lane >> 3;
    const int lc   = (lane & 7) ^ lrow;
    const unsigned short* aSrc = A  + (size_t)(tm * BM + wave * 8 + lrow) * KK + lc * 8;
    const unsigned short* bSrc = Bw + (size_t)(tn * BN + wave * 8 + lrow) * KK + lc * 8;
    const int wblk = wave * 1024;

#define STAGE(srcBase, rowsOff, kOff, ldsPtr) do {                                          \
        gload_lds16((srcBase) + (size_t)(rowsOff) * KK + (kOff), (ldsPtr) + wblk);          \
        gload_lds16((srcBase) + (size_t)((rowsOff) + 64) * KK + (kOff), (ldsPtr) + 8192 + wblk); \
    } while (0)

    // ---- compute lane constants (R2-proven geometry) ----
    const int r7  = lane & 7;
    const int l15 = lane & 15;
    const int c0  = (((lane >> 4)    ) ^ r7) * 16;   // kk0 phys chunk byte
    const int c1  = (((lane >> 4) + 4) ^ r7) * 16;   // kk1 phys chunk byte
    const int aoff = (wm * 128 + l15) * 128;         // A row byte offset (mf adds 2048)
    const int boff = (wn * 64  + l15) * 128;         // B row byte offset (nf adds 2048)

    // ---- prologue: A(0)->buf0, B(0)->buf0, A(1)->buf1 (oldest first) ----
    STAGE(aSrc, 0,   0, lds + 0);
    STAGE(aSrc, 128, 0, lds + 16384);
    STAGE(bSrc, 0,   0, lds + 32768);
    STAGE(bSrc, 128, 0, lds + 32768 + 16384);
    STAGE(aSrc, 0,   BK, lds + 65536);
    STAGE(aSrc, 128, BK, lds + 65536 + 16384);
    asm volatile("s_waitcnt vmcnt(4)" ::: "memory");   // A(0),B(0) landed; A(1) in flight
    BARF();

#define MFMA8(AARR, BREG, NF)                                                     \
    _Pragma("unroll")                                                             \
    for (int mf = 0; mf < 8; ++mf)                                                \
        acc[mf][NF] = __builtin_amdgcn_mfma_f32_16x16x32_bf16(                    \
            AARR[mf], BREG, acc[mf][NF], 0, 0, 0);

#pragma unroll 2
    for (int t = 0; t < TT; ++t) {
        const char* Ab = lds + ((t & 1) << 16);
        const char* Bb = Ab + 32768;
        char* BstN = lds + (((t & 1) ^ 1) << 16) + 32768;   // B(t+1) dest (other buf)
        char* AstN = lds + ((t & 1) << 16);                  // A(t+2) dest (in-place)
        const bool pfB = (t + 1 < TT);
        const bool pfA = (t + 2 < TT);
        const int kB = (t + 1) * BK;
        const int kA = (t + 2) * BK;

        // ---- c1: reads b00,b01 + a0[8]; stage B(t+1); MFMA a0 x {b00,b01} ----
        bf16x8 b00 = *(const bf16x8*)(Bb + boff + 0 * 2048 + c0);
        bf16x8 b01 = *(const bf16x8*)(Bb + boff + 1 * 2048 + c0);
        bf16x8 a0[8];
#pragma unroll
        for (int mf = 0; mf < 8; ++mf)
            a0[mf] = *(const bf16x8*)(Ab + aoff + mf * 2048 + c0);
        if (pfB) {
            STAGE(bSrc, 0,   kB, BstN);
            STAGE(bSrc, 128, kB, BstN + 16384);
        }
        __builtin_amdgcn_s_setprio(1);
        MFMA8(a0, b00, 0); MFMA8(a0, b01, 1);
        __builtin_amdgcn_s_setprio(0);

        // ---- c2: reads b02,b03; MFMA a0 x {b02,b03} (a0 dies here) ----
        bf16x8 b02 = *(const bf16x8*)(Bb + boff + 2 * 2048 + c0);
        bf16x8 b03 = *(const bf16x8*)(Bb + boff + 3 * 2048 + c0);
        __builtin_amdgcn_s_setprio(1);
        MFMA8(a0, b02, 2); MFMA8(a0, b03, 3);
        __builtin_amdgcn_s_setprio(0);

        // ---- c3: reads a1[8] + b10,b11; A-DRAIN GATE; MFMA a1 x {b10,b11} ----
        bf16x8 a1[8];
#pragma unroll
        for (int mf = 0; mf < 8; ++mf)
            a1[mf] = *(const bf16x8*)(Ab + aoff + mf * 2048 + c1);
        bf16x8 b10 = *(const bf16x8*)(Bb + boff + 0 * 2048 + c1);
        bf16x8 b11 = *(const bf16x8*)(Bb + boff + 1 * 2048 + c1);
        LGKM0();        // this wave's A-reads (a0,a1) all complete
        BARF();         // => block-wide A-buffer drain before any A(t+2) stage
        __builtin_amdgcn_s_setprio(1);
        MFMA8(a1, b10, 0); MFMA8(a1, b11, 1);
        __builtin_amdgcn_s_setprio(0);

        // ---- c4: reads b12,b13; stage A(t+2) in-place; MFMA; tile gate ----
        bf16x8 b12 = *(const bf16x8*)(Bb + boff + 2 * 2048 + c1);
        bf16x8 b13 = *(const bf16x8*)(Bb + boff + 3 * 2048 + c1);
        if (pfA) {
            STAGE(aSrc, 0,   kA, AstN);
            STAGE(aSrc, 128, kA, AstN + 16384);
        }
        __builtin_amdgcn_s_setprio(1);
        MFMA8(a1, b12, 2); MFMA8(a1, b13, 3);
        __builtin_amdgcn_s_setprio(0);
        if (t < TT - 1) {
            if (pfA) { asm volatile("s_waitcnt vmcnt(4)" ::: "memory"); }
            else     { asm volatile("s_waitcnt vmcnt(0)" ::: "memory"); }
            BARF();   // tile gate: A(t+1),B(t+1) landed block-wide
        }
    }
#undef MFMA8
#undef STAGE

    // ---- epilogue: C/D layout col=lane&15, row=(lane>>4)*4+j; fuse bias ----
    const int crow = tm * BM + wm * 128 + (lane >> 4) * 4;
    const int ccol = tn * BN + wn * 64 + l15;
    float bv[4];
#pragma unroll
    for (int nf = 0; nf < 4; ++nf) bv[nf] = bias[ccol + nf * 16];
#pragma unroll
    for (int mf = 0; mf < 8; ++mf)
#pragma unroll
        for (int nf = 0; nf < 4; ++nf)
#pragma unroll
            for (int j = 0; j < 4; ++j)
                C[(size_t)(crow + mf * 16 + j) * NN + ccol + nf * 16] =
                    acc[mf][nf][j] + bv[nf];
}

// ================= fallback: fused 128x128 (R1, known-correct) =================
__global__ __launch_bounds__(256) void gemm_fused_kernel(
    const float* __restrict__ Af,
    const int* __restrict__ Wq,
    const float* __restrict__ snz,
    const float* __restrict__ bias,
    float* __restrict__ C)
{
    __shared__ alignas(16) unsigned short As[128 * 64];
    __shared__ alignas(16) unsigned short Bs[128 * 64];

    const int tid  = threadIdx.x;
    const int lane = tid & 63;
    const int wave = tid >> 6;

    const int NTN = NN / 128;
    const int nwg = (MM / 128) * NTN;
    const int cpx = nwg >> 3;
    int wg = ((int)blockIdx.x & 7) * cpx + ((int)blockIdx.x >> 3);
    const int tm = wg / NTN;
    const int tn = wg - tm * NTN;

    const int wm = wave >> 1, wn = wave & 1;

    f32x4 acc[4][4] = {};

    const int r7  = lane & 7;
    const int pc0 = (((lane >> 4)    ) ^ r7) * 16;
    const int pc1 = (((lane >> 4) + 4) ^ r7) * 16;
    const int arow = wm * 64 + (lane & 15);
    const int brow = wn * 64 + (lane & 15);
    const char* AsR = (const char*)As;
    const char* BsR = (const char*)Bs;

    const int frow = tid >> 1;
    const int fh   = tid & 1;
    const int frx  = frow & 7;

    for (int k0 = 0; k0 < KK; k0 += 64) {
        {
            const float* ap = Af + (size_t)(tm * 128 + frow) * KK + k0 + fh * 32;
#pragma unroll
            for (int c = 0; c < 4; ++c) {
                float4 x = ((const float4*)ap)[2 * c];
                float4 y = ((const float4*)ap)[2 * c + 1];
                union { unsigned short h[8]; uint4 v; } u;
                u.h[0] = f2bf(x.x); u.h[1] = f2bf(x.y); u.h[2] = f2bf(x.z); u.h[3] = f2bf(x.w);
                u.h[4] = f2bf(y.x); u.h[5] = f2bf(y.y); u.h[6] = f2bf(y.z); u.h[7] = f2bf(y.w);
                int lc2 = fh * 4 + c;
                *(uint4*)&As[frow * 64 + ((lc2 ^ frx) * 8)] = u.v;
            }
        }
        {
            const int nrow = tn * 128 + frow;
            const int* wp = Wq + (size_t)nrow * KK + k0 + fh * 32;
            float2 sz = ((const float2*)snz)[(size_t)((k0 >> 5) + fh) * NN + nrow];
#pragma unroll
            for (int c = 0; c < 4; ++c) {
                int4 q0 = ((const int4*)wp)[2 * c];
                int4 q1 = ((const int4*)wp)[2 * c + 1];
                union { unsigned short h[8]; uint4 v; } u;
                u.h[0] = f2bf((float)(q0.x - 8) * sz.x + sz.y);
                u.h[1] = f2bf((float)(q0.y - 8) * sz.x + sz.y);
                u.h[2] = f2bf((float)(q0.z - 8) * sz.x + sz.y);
                u.h[3] = f2bf((float)(q0.w - 8) * sz.x + sz.y);
                u.h[4] = f2bf((float)(q1.x - 8) * sz.x + sz.y);
                u.h[5] = f2bf((float)(q1.y - 8) * sz.x + sz.y);
                u.h[6] = f2bf((float)(q1.z - 8) * sz.x + sz.y);
                u.h[7] = f2bf((float)(q1.w - 8) * sz.x + sz.y);
                int lc2 = fh * 4 + c;
                *(uint4*)&Bs[frow * 64 + ((lc2 ^ frx) * 8)] = u.v;
            }
        }
        __syncthreads();
        {
            bf16x8 af[4], bfr[4];
#pragma unroll
            for (int x = 0; x < 4; ++x) {
                af[x]  = *(const bf16x8*)(AsR + (arow + x * 16) * 128 + pc0);
                bfr[x] = *(const bf16x8*)(BsR + (brow + x * 16) * 128 + pc0);
            }
#pragma unroll
            for (int mi = 0; mi < 4; ++mi)
#pragma unroll
                for (int ni = 0; ni < 4; ++ni)
                    acc[mi][ni] = __builtin_amdgcn_mfma_f32_16x16x32_bf16(
                        af[mi], bfr[ni], acc[mi][ni], 0, 0, 0);
        }
        {
            bf16x8 af[4], bfr[4];
#pragma unroll
            for (int x = 0; x < 4; ++x) {
                af[x]  = *(const bf16x8*)(AsR + (arow + x * 16) * 128 + pc1);
                bfr[x] = *(const bf16x8*)(BsR + (brow + x * 16) * 128 + pc1);
            }
#pragma unroll
            for (int mi = 0; mi < 4; ++mi)
#pragma unroll
                for (int ni = 0; ni < 4; ++ni)
                    acc[mi][ni] = __builtin_amdgcn_mfma_f32_16x16x32_bf16(
                        af[mi], bfr[ni], acc[mi][ni], 0, 0, 0);
        }
        __syncthreads();
    }

    const int crow = tm * 128 + wm * 64 + (lane >> 4) * 4;
    const int ccol = tn * 128 + wn * 64 + (lane & 15);
    float bv[4];
#pragma unroll
    for (int ni = 0; ni < 4; ++ni) bv[ni] = bias[ccol + ni * 16];
#pragma unroll
    for (int mi = 0; mi < 4; ++mi)
#pragma unroll
        for (int ni = 0; ni < 4; ++ni)
#pragma unroll
            for (int j = 0; j < 4; ++j)
                C[(size_t)(crow + mi * 16 + j) * NN + ccol + ni * 16] =
                    acc[mi][ni][j] + bv[ni];
}

extern "C" void kernel_launch(void* const* d_in, const int* in_sizes, int n_in,
                              void* d_out, int out_size, void* d_ws, size_t ws_size,
                              hipStream_t stream)
{
    const float* inA  = (const float*)d_in[0];   // [M,K] fp32
    const int*   Wq   = (const int*)d_in[1];     // [N,K] int codes
    const float* snz  = (const float*)d_in[2];   // [K/32,N,2] fp32
    const float* bias = (const float*)d_in[3];   // [N] fp32
    float* out = (float*)d_out;

    const size_t needA = (size_t)MM * KK * 2;
    const size_t needW = (size_t)NN * KK * 2;

    if (ws_size >= needA + needW) {
        unsigned short* Abf = (unsigned short*)d_ws;
        unsigned short* Wbf = (unsigned short*)((char*)d_ws + needA);
        cvt_a_kernel<<<(MM * KK / 8) / 256, 256, 0, stream>>>(inA, Abf);
        dq_w_kernel<<<(NN * KK / 8) / 256, 256, 0, stream>>>(Wq, snz, Wbf);
        gemm256_kernel<<<(MM / BM) * (NN / BN), 512, 0, stream>>>(Abf, Wbf, bias, out);
    } else {
        gemm_fused_kernel<<<(MM / 128) * (NN / 128), 256, 0, stream>>>(
            inA, Wq, snz, bias, out);
    }
}

// Round 6
// 793.606 us; speedup vs baseline: 3.0026x; 1.0251x over previous
//
#include <hip/hip_runtime.h>
#include <hip/hip_bf16.h>
#include <cstdint>
#include <cstddef>

// Problem constants (fixed by the harness problem instance).
#define MM 8192
#define KK 4096
#define NN 12288

typedef __bf16 bf16x8 __attribute__((ext_vector_type(8)));
typedef float  f32x4  __attribute__((ext_vector_type(4)));

// fp32 -> bf16 round-to-nearest-even (finite inputs).
__device__ __forceinline__ unsigned short f2bf(float f) {
    union { float f; unsigned int u; } v; v.f = f;
    unsigned int r = v.u + 0x7fffu + ((v.u >> 16) & 1u);
    return (unsigned short)(r >> 16);
}

// async global->LDS, 16 B per lane. LDS dest is wave-uniform base + lane*16.
__device__ __forceinline__ void gload_lds16(const void* g, void* l) {
    __builtin_amdgcn_global_load_lds(
        (__attribute__((address_space(1))) void*)g,
        (__attribute__((address_space(3))) void*)l,
        16, 0, 0);
}

#define FENCE() asm volatile("" ::: "memory")
#define BARF()  do { FENCE(); __builtin_amdgcn_s_barrier(); FENCE(); } while (0)

// ---------------- pre-pass 1: input fp32 -> bf16 ----------------
__global__ __launch_bounds__(256) void cvt_a_kernel(
    const float* __restrict__ in, unsigned short* __restrict__ out)
{
    size_t i = (size_t)blockIdx.x * 256 + threadIdx.x;   // 8 elems / thread
    const float4* p = (const float4*)in;
    float4 x = p[2 * i], y = p[2 * i + 1];
    union { unsigned short h[8]; uint4 v; } u;
    u.h[0] = f2bf(x.x); u.h[1] = f2bf(x.y); u.h[2] = f2bf(x.z); u.h[3] = f2bf(x.w);
    u.h[4] = f2bf(y.x); u.h[5] = f2bf(y.y); u.h[6] = f2bf(y.z); u.h[7] = f2bf(y.w);
    ((uint4*)out)[i] = u.v;
}

// ---------------- pre-pass 2: dequant int4 codes -> bf16 [N,K] ----------------
__global__ __launch_bounds__(256) void dq_w_kernel(
    const int* __restrict__ w, const float* __restrict__ snz,
    unsigned short* __restrict__ out)
{
    size_t t = (size_t)blockIdx.x * 256 + threadIdx.x;   // 8 codes / thread
    int kc = (int)(t & (KK / 8 - 1));                    // K/8 = 512
    int n  = (int)(t >> 9);
    int g  = kc >> 2;                                    // 32 codes per group
    float2 sz = ((const float2*)snz)[(size_t)g * NN + n];  // {scale, zero}
    const int4* wp = (const int4*)w;
    int4 q0 = wp[2 * t], q1 = wp[2 * t + 1];
    union { unsigned short h[8]; uint4 v; } u;
    u.h[0] = f2bf((float)(q0.x - 8) * sz.x + sz.y);
    u.h[1] = f2bf((float)(q0.y - 8) * sz.x + sz.y);
    u.h[2] = f2bf((float)(q0.z - 8) * sz.x + sz.y);
    u.h[3] = f2bf((float)(q0.w - 8) * sz.x + sz.y);
    u.h[4] = f2bf((float)(q1.x - 8) * sz.x + sz.y);
    u.h[5] = f2bf((float)(q1.y - 8) * sz.x + sz.y);
    u.h[6] = f2bf((float)(q1.z - 8) * sz.x + sz.y);
    u.h[7] = f2bf((float)(q1.w - 8) * sz.x + sz.y);
    ((uint4*)out)[t] = u.v;
}

// ================= 256x256 GEMM, single-gate schedule =================
// C[M,N] = A[M,K](bf16) * W[N,K](bf16)^T + bias, fp32 out.
// 8 waves (2M x 4N), wave output 128x64, acc[8][4] f32x4 (AGPR).
// LDS 160 KiB: A TRIPLE-buffered (3 x 32 KiB @ 0/32768/65536),
//              B double-buffered  (2 x 32 KiB @ 98304/131072).
// 128-B rows, chunk-XOR swizzle (phys = logical ^ (row&7)) on write-src & read.
//
// ONE barrier + ONE counted vmcnt per K-tile (no mid-tile gate):
//  - Stage B(t+1)->Bbuf[(t+1)&1] (c1) overwrites B(t-1); those reads were
//    consumed before tile (t-1)'s closing barrier (a wave reaches the barrier
//    only after its MFMAs, which require its ds_reads complete). Safe.
//  - Stage A(t+2)->Abuf[(t+2)%3] (c3) overwrites A(t-1); same argument. Safe.
//    (Triple-buffering A removes R5's in-place hazard => no lgkmcnt(0) gate.)
//  - End-of-tile: outstanding DMA = A(t+1)[4 carried] + B(t+1)[4] + A(t+2)[4];
//    vmcnt(4) drains A(t+1),B(t+1) (everything tile t+1 reads), leaves A(t+2)
//    in flight. vmcnt(0) once staging stops. lgkmcnt: compiler fine-grained.
#define BM 256
#define BN 256
#define BK 64
#define TT (KK / BK)   // 64

__global__ __launch_bounds__(512, 2) void gemm256_kernel(
    const unsigned short* __restrict__ A,    // bf16 [M,K]
    const unsigned short* __restrict__ Bw,   // bf16 [N,K]
    const float* __restrict__ bias,          // [N]
    float* __restrict__ C)                   // fp32 [M,N]
{
    __shared__ char lds[163840];

    const int tid  = threadIdx.x;
    const int lane = tid & 63;
    const int wave = tid >> 6;            // 0..7
    const int wm   = wave >> 2;           // 0..1
    const int wn   = wave & 3;            // 0..3

    // XCD-aware swizzle (nwg = 32*48 = 1536, divisible by 8).
    const int NTN = NN / BN;              // 48
    const int nwg = (MM / BM) * NTN;      // 1536
    const int cpx = nwg >> 3;             // 192
    int wg = ((int)blockIdx.x & 7) * cpx + ((int)blockIdx.x >> 3);
    const int tm = wg / NTN;
    const int tn = wg - tm * NTN;

    f32x4 acc[8][4] = {};

    // ---- staging lane constants (R2-proven geometry) ----
    const int lrow = lane >> 3;
    const int lc   = (lane & 7) ^ lrow;
    const unsigned short* aSrc = A  + (size_t)(tm * BM + wave * 8 + lrow) * KK + lc * 8;
    const unsigned short* bSrc = Bw + (size_t)(tn * BN + wave * 8 + lrow) * KK + lc * 8;
    const int wblk = wave * 1024;

#define STAGE(srcBase, rowsOff, kOff, ldsPtr) do {                                          \
        gload_lds16((srcBase) + (size_t)(rowsOff) * KK + (kOff), (ldsPtr) + wblk);          \
        gload_lds16((srcBase) + (size_t)((rowsOff) + 64) * KK + (kOff), (ldsPtr) + 8192 + wblk); \
    } while (0)

    // ---- compute lane constants (R2-proven geometry) ----
    const int r7  = lane & 7;
    const int l15 = lane & 15;
    const int c0  = (((lane >> 4)    ) ^ r7) * 16;   // kk0 phys chunk byte
    const int c1  = (((lane >> 4) + 4) ^ r7) * 16;   // kk1 phys chunk byte
    const int aoff = (wm * 128 + l15) * 128;         // A row byte offset (mf adds 2048)
    const int boff = (wn * 64  + l15) * 128;         // B row byte offset (nf adds 2048)

    char* const Ab0 = lds;                 // A buffers: 3 x 32 KiB
    char* const Bb0 = lds + 98304;         // B buffers: 2 x 32 KiB

    // ---- prologue: A(0)->Ab[0], B(0)->Bb[0], A(1)->Ab[1] (oldest first) ----
    STAGE(aSrc, 0,   0, Ab0);
    STAGE(aSrc, 128, 0, Ab0 + 16384);
    STAGE(bSrc, 0,   0, Bb0);
    STAGE(bSrc, 128, 0, Bb0 + 16384);
    STAGE(aSrc, 0,   BK, Ab0 + 32768);
    STAGE(aSrc, 128, BK, Ab0 + 32768 + 16384);
    asm volatile("s_waitcnt vmcnt(4)" ::: "memory");   // A(0),B(0) landed; A(1) in flight
    BARF();

#define MFMA8(AARR, BREG, NF)                                                     \
    _Pragma("unroll")                                                             \
    for (int mf = 0; mf < 8; ++mf)                                                \
        acc[mf][NF] = __builtin_amdgcn_mfma_f32_16x16x32_bf16(                    \
            AARR[mf], BREG, acc[mf][NF], 0, 0, 0);

    int aR = 0;   // t % 3 (A read buffer)
#pragma unroll 1
    for (int t = 0; t < TT; ++t) {
        const char* Ab = Ab0 + (aR << 15);
        const char* Bb = Bb0 + ((t & 1) << 15);
        char* BstN = Bb0 + (((t & 1) ^ 1) << 15);        // B(t+1) dest
        const int aS = (aR == 0) ? 2 : aR - 1;           // (t+2) % 3
        char* AstN = Ab0 + (aS << 15);                   // A(t+2) dest
        const bool pfB = (t + 1 < TT);
        const bool pfA = (t + 2 < TT);
        const int kB = (t + 1) * BK;
        const int kA = (t + 2) * BK;

        // ---- c1: reads b00,b01 + a0[8]; stage B(t+1); MFMA a0 x {b00,b01} ----
        bf16x8 b00 = *(const bf16x8*)(Bb + boff + 0 * 2048 + c0);
        bf16x8 b01 = *(const bf16x8*)(Bb + boff + 1 * 2048 + c0);
        bf16x8 a0[8];
#pragma unroll
        for (int mf = 0; mf < 8; ++mf)
            a0[mf] = *(const bf16x8*)(Ab + aoff + mf * 2048 + c0);
        if (pfB) {
            STAGE(bSrc, 0,   kB, BstN);
            STAGE(bSrc, 128, kB, BstN + 16384);
        }
        __builtin_amdgcn_s_setprio(1);
        MFMA8(a0, b00, 0); MFMA8(a0, b01, 1);
        __builtin_amdgcn_s_setprio(0);

        // ---- c2: reads b02,b03; MFMA a0 x {b02,b03} (a0 dies here) ----
        bf16x8 b02 = *(const bf16x8*)(Bb + boff + 2 * 2048 + c0);
        bf16x8 b03 = *(const bf16x8*)(Bb + boff + 3 * 2048 + c0);
        __builtin_amdgcn_s_setprio(1);
        MFMA8(a0, b02, 2); MFMA8(a0, b03, 3);
        __builtin_amdgcn_s_setprio(0);

        // ---- c3: reads a1[8] + b10,b11; stage A(t+2); MFMA a1 x {b10,b11} ----
        bf16x8 a1[8];
#pragma unroll
        for (int mf = 0; mf < 8; ++mf)
            a1[mf] = *(const bf16x8*)(Ab + aoff + mf * 2048 + c1);
        bf16x8 b10 = *(const bf16x8*)(Bb + boff + 0 * 2048 + c1);
        bf16x8 b11 = *(const bf16x8*)(Bb + boff + 1 * 2048 + c1);
        if (pfA) {
            STAGE(aSrc, 0,   kA, AstN);
            STAGE(aSrc, 128, kA, AstN + 16384);
        }
        __builtin_amdgcn_s_setprio(1);
        MFMA8(a1, b10, 0); MFMA8(a1, b11, 1);
        __builtin_amdgcn_s_setprio(0);

        // ---- c4: reads b12,b13; MFMA a1 x {b12,b13}; single tile gate ----
        bf16x8 b12 = *(const bf16x8*)(Bb + boff + 2 * 2048 + c1);
        bf16x8 b13 = *(const bf16x8*)(Bb + boff + 3 * 2048 + c1);
        __builtin_amdgcn_s_setprio(1);
        MFMA8(a1, b12, 2); MFMA8(a1, b13, 3);
        __builtin_amdgcn_s_setprio(0);
        if (t < TT - 1) {
            if (pfA) { asm volatile("s_waitcnt vmcnt(4)" ::: "memory"); }
            else     { asm volatile("s_waitcnt vmcnt(0)" ::: "memory"); }
            BARF();   // tile gate: A(t+1),B(t+1) landed; tile-t reads consumed
        }
        aR = (aR == 2) ? 0 : aR + 1;
    }
#undef MFMA8
#undef STAGE

    // ---- epilogue: C/D layout col=lane&15, row=(lane>>4)*4+j; fuse bias ----
    const int crow = tm * BM + wm * 128 + (lane >> 4) * 4;
    const int ccol = tn * BN + wn * 64 + l15;
    float bv[4];
#pragma unroll
    for (int nf = 0; nf < 4; ++nf) bv[nf] = bias[ccol + nf * 16];
#pragma unroll
    for (int mf = 0; mf < 8; ++mf)
#pragma unroll
        for (int nf = 0; nf < 4; ++nf)
#pragma unroll
            for (int j = 0; j < 4; ++j)
                C[(size_t)(crow + mf * 16 + j) * NN + ccol + nf * 16] =
                    acc[mf][nf][j] + bv[nf];
}

// ================= fallback: fused 128x128 (R1, known-correct) =================
__global__ __launch_bounds__(256) void gemm_fused_kernel(
    const float* __restrict__ Af,
    const int* __restrict__ Wq,
    const float* __restrict__ snz,
    const float* __restrict__ bias,
    float* __restrict__ C)
{
    __shared__ alignas(16) unsigned short As[128 * 64];
    __shared__ alignas(16) unsigned short Bs[128 * 64];

    const int tid  = threadIdx.x;
    const int lane = tid & 63;
    const int wave = tid >> 6;

    const int NTN = NN / 128;
    const int nwg = (MM / 128) * NTN;
    const int cpx = nwg >> 3;
    int wg = ((int)blockIdx.x & 7) * cpx + ((int)blockIdx.x >> 3);
    const int tm = wg / NTN;
    const int tn = wg - tm * NTN;

    const int wm = wave >> 1, wn = wave & 1;

    f32x4 acc[4][4] = {};

    const int r7  = lane & 7;
    const int pc0 = (((lane >> 4)    ) ^ r7) * 16;
    const int pc1 = (((lane >> 4) + 4) ^ r7) * 16;
    const int arow = wm * 64 + (lane & 15);
    const int brow = wn * 64 + (lane & 15);
    const char* AsR = (const char*)As;
    const char* BsR = (const char*)Bs;

    const int frow = tid >> 1;
    const int fh   = tid & 1;
    const int frx  = frow & 7;

    for (int k0 = 0; k0 < KK; k0 += 64) {
        {
            const float* ap = Af + (size_t)(tm * 128 + frow) * KK + k0 + fh * 32;
#pragma unroll
            for (int c = 0; c < 4; ++c) {
                float4 x = ((const float4*)ap)[2 * c];
                float4 y = ((const float4*)ap)[2 * c + 1];
                union { unsigned short h[8]; uint4 v; } u;
                u.h[0] = f2bf(x.x); u.h[1] = f2bf(x.y); u.h[2] = f2bf(x.z); u.h[3] = f2bf(x.w);
                u.h[4] = f2bf(y.x); u.h[5] = f2bf(y.y); u.h[6] = f2bf(y.z); u.h[7] = f2bf(y.w);
                int lc2 = fh * 4 + c;
                *(uint4*)&As[frow * 64 + ((lc2 ^ frx) * 8)] = u.v;
            }
        }
        {
            const int nrow = tn * 128 + frow;
            const int* wp = Wq + (size_t)nrow * KK + k0 + fh * 32;
            float2 sz = ((const float2*)snz)[(size_t)((k0 >> 5) + fh) * NN + nrow];
#pragma unroll
            for (int c = 0; c < 4; ++c) {
                int4 q0 = ((const int4*)wp)[2 * c];
                int4 q1 = ((const int4*)wp)[2 * c + 1];
                union { unsigned short h[8]; uint4 v; } u;
                u.h[0] = f2bf((float)(q0.x - 8) * sz.x + sz.y);
                u.h[1] = f2bf((float)(q0.y - 8) * sz.x + sz.y);
                u.h[2] = f2bf((float)(q0.z - 8) * sz.x + sz.y);
                u.h[3] = f2bf((float)(q0.w - 8) * sz.x + sz.y);
                u.h[4] = f2bf((float)(q1.x - 8) * sz.x + sz.y);
                u.h[5] = f2bf((float)(q1.y - 8) * sz.x + sz.y);
                u.h[6] = f2bf((float)(q1.z - 8) * sz.x + sz.y);
                u.h[7] = f2bf((float)(q1.w - 8) * sz.x + sz.y);
                int lc2 = fh * 4 + c;
                *(uint4*)&Bs[frow * 64 + ((lc2 ^ frx) * 8)] = u.v;
            }
        }
        __syncthreads();
        {
            bf16x8 af[4], bfr[4];
#pragma unroll
            for (int x = 0; x < 4; ++x) {
                af[x]  = *(const bf16x8*)(AsR + (arow + x * 16) * 128 + pc0);
                bfr[x] = *(const bf16x8*)(BsR + (brow + x * 16) * 128 + pc0);
            }
#pragma unroll
            for (int mi = 0; mi < 4; ++mi)
#pragma unroll
                for (int ni = 0; ni < 4; ++ni)
                    acc[mi][ni] = __builtin_amdgcn_mfma_f32_16x16x32_bf16(
                        af[mi], bfr[ni], acc[mi][ni], 0, 0, 0);
        }
        {
            bf16x8 af[4], bfr[4];
#pragma unroll
            for (int x = 0; x < 4; ++x) {
                af[x]  = *(const bf16x8*)(AsR + (arow + x * 16) * 128 + pc1);
                bfr[x] = *(const bf16x8*)(BsR + (brow + x * 16) * 128 + pc1);
            }
#pragma unroll
            for (int mi = 0; mi < 4; ++mi)
#pragma unroll
                for (int ni = 0; ni < 4; ++ni)
                    acc[mi][ni] = __builtin_amdgcn_mfma_f32_16x16x32_bf16(
                        af[mi], bfr[ni], acc[mi][ni], 0, 0, 0);
        }
        __syncthreads();
    }

    const int crow = tm * 128 + wm * 64 + (lane >> 4) * 4;
    const int ccol = tn * 128 + wn * 64 + (lane & 15);
    float bv[4];
#pragma unroll
    for (int ni = 0; ni < 4; ++ni) bv[ni] = bias[ccol + ni * 16];
#pragma unroll
    for (int mi = 0; mi < 4; ++mi)
#pragma unroll
        for (int ni = 0; ni < 4; ++ni)
#pragma unroll
            for (int j = 0; j < 4; ++j)
                C[(size_t)(crow + mi * 16 + j) * NN + ccol + ni * 16] =
                    acc[mi][ni][j] + bv[ni];
}

extern "C" void kernel_launch(void* const* d_in, const int* in_sizes, int n_in,
                              void* d_out, int out_size, void* d_ws, size_t ws_size,
                              hipStream_t stream)
{
    const float* inA  = (const float*)d_in[0];   // [M,K] fp32
    const int*   Wq   = (const int*)d_in[1];     // [N,K] int codes
    const float* snz  = (const float*)d_in[2];   // [K/32,N,2] fp32
    const float* bias = (const float*)d_in[3];   // [N] fp32
    float* out = (float*)d_out;

    const size_t needA = (size_t)MM * KK * 2;
    const size_t needW = (size_t)NN * KK * 2;

    if (ws_size >= needA + needW) {
        unsigned short* Abf = (unsigned short*)d_ws;
        unsigned short* Wbf = (unsigned short*)((char*)d_ws + needA);
        cvt_a_kernel<<<(MM * KK / 8) / 256, 256, 0, stream>>>(inA, Abf);
        dq_w_kernel<<<(NN * KK / 8) / 256, 256, 0, stream>>>(Wq, snz, Wbf);
        gemm256_kernel<<<(MM / BM) * (NN / BN), 512, 0, stream>>>(Abf, Wbf, bias, out);
    } else {
        gemm_fused_kernel<<<(MM / 128) * (NN / 128), 256, 0, stream>>>(
            inA, Wq, snz, bias, out);
    }
}